// Round 1
// baseline (880.549 us; speedup 1.0000x reference)
//
#include <hip/hip_runtime.h>
#include <hip/hip_bf16.h>

#define NN 50000
#define NE 800000
#define HD 128
#define G3 384   // 3*H
#define K2 256   // 2*H

// ---------------- CSR build ----------------
__global__ void k_deg(const int* __restrict__ edges, int* __restrict__ deg) {
    int e = blockIdx.x * blockDim.x + threadIdx.x;
    if (e < NE) atomicAdd(&deg[edges[2 * e + 1]], 1);
}

__global__ void k_scan(const int* __restrict__ deg, int* __restrict__ off,
                       int* __restrict__ cur) {
    __shared__ int sm[1024];
    __shared__ int carry_s;
    int tid = threadIdx.x;
    if (tid == 0) carry_s = 0;
    __syncthreads();
    for (int base = 0; base < NN; base += 1024) {
        int i = base + tid;
        int v = (i < NN) ? deg[i] : 0;
        sm[tid] = v;
        __syncthreads();
        for (int ofs = 1; ofs < 1024; ofs <<= 1) {
            int t = (tid >= ofs) ? sm[tid - ofs] : 0;
            __syncthreads();
            sm[tid] += t;
            __syncthreads();
        }
        int incl = sm[tid];
        int carry = carry_s;
        if (i < NN) {
            int ex = carry + incl - v;
            off[i] = ex;
            cur[i] = ex;
        }
        __syncthreads();
        if (tid == 1023) carry_s = carry + incl;
        __syncthreads();
    }
}

__global__ void k_fill(const int* __restrict__ edges, int* __restrict__ cur,
                       int* __restrict__ csr_src) {
    int e = blockIdx.x * blockDim.x + threadIdx.x;
    if (e < NE) {
        int s = edges[2 * e];
        int d = edges[2 * e + 1];
        int pos = atomicAdd(&cur[d], 1);
        csr_src[pos] = s;
    }
}

// ---------------- combined weights ----------------
// B1[t][k][n] = sum_j W_ih[t][n][j] * W_msg[t][j][k]   (k<256, n<384)
__global__ void k_comb1(const float* __restrict__ W_ih, const float* __restrict__ W_msg,
                        float* __restrict__ B1) {
    int idx = blockIdx.x * blockDim.x + threadIdx.x;
    if (idx >= 2 * K2 * G3) return;
    int k = idx % K2;
    int n = (idx / K2) % G3;
    int t = idx / (K2 * G3);
    const float* wi = W_ih + ((size_t)t * G3 + n) * K2;
    const float* wm = W_msg + (size_t)t * K2 * K2;
    float acc = 0.f;
#pragma unroll 8
    for (int j = 0; j < K2; j++) acc += wi[j] * wm[(size_t)j * K2 + k];
    B1[((size_t)t * K2 + k) * G3 + n] = acc;
}

// c3[t][n] = sum_j W_ih[t][n][j] * b_msg[t][j]
__global__ void k_comb3(const float* __restrict__ W_ih, const float* __restrict__ b_msg,
                        float* __restrict__ c3) {
    int idx = blockIdx.x * blockDim.x + threadIdx.x;
    if (idx >= 2 * G3) return;
    int n = idx % G3;
    int t = idx / G3;
    const float* wi = W_ih + ((size_t)t * G3 + n) * K2;
    const float* bm = b_msg + t * K2;
    float acc = 0.f;
#pragma unroll 8
    for (int j = 0; j < K2; j++) acc += wi[j] * bm[j];
    c3[idx] = acc;
}

// B2[t][k][n] = W_hh[t][n][k]   (k<128, n<384)
__global__ void k_comb2(const float* __restrict__ W_hh, float* __restrict__ B2) {
    int idx = blockIdx.x * blockDim.x + threadIdx.x;
    if (idx >= 2 * HD * G3) return;
    int k = idx % HD;
    int n = (idx / HD) % G3;
    int t = idx / (HD * G3);
    B2[((size_t)t * HD + k) * G3 + n] = W_hh[((size_t)t * G3 + n) * HD + k];
}

// ---------------- aggregation: s[v] = sum_{e: dst=v} h[src_e] ----------------
__global__ void k_agg(const float* __restrict__ h, const int* __restrict__ off,
                      const int* __restrict__ deg, const int* __restrict__ csr_src,
                      float* __restrict__ sbuf) {
    int wave = (blockIdx.x * blockDim.x + threadIdx.x) >> 6;
    int lane = threadIdx.x & 63;
    if (wave >= NN) return;
    int start = off[wave];
    int d = deg[wave];
    float a0 = 0.f, a1 = 0.f;
    for (int j = 0; j < d; j++) {
        int src = csr_src[start + j];
        float2 v = *reinterpret_cast<const float2*>(h + (size_t)src * HD + lane * 2);
        a0 += v.x;
        a1 += v.y;
    }
    *reinterpret_cast<float2*>(sbuf + (size_t)wave * HD + lane * 2) = make_float2(a0, a1);
}

// ---------------- tiled f32 GEMM: C[m][n] = sum_k A[m][k]*B[k][n] + epilogue ----
// SPLIT: A[m][k] = (k<128) ? s[m][k] : deg[m]*h[m][k-128]; epilogue += deg*c3 + bias
// else : A[m][k] = h[m][k];                               epilogue += bias
template <int KTOT, bool SPLIT>
__global__ __launch_bounds__(256) void k_gemm(const float* __restrict__ A1,
                                              const float* __restrict__ A2,
                                              const int* __restrict__ deg,
                                              const float* __restrict__ B,
                                              const float* __restrict__ bias,
                                              const float* __restrict__ c3,
                                              float* __restrict__ C) {
    const int BM = 64, BN = 64, BK = 32;
    __shared__ float As[BK][BM + 4];
    __shared__ float Bs[BK][BN + 4];
    int tid = threadIdx.x;
    int tx = tid & 15;
    int ty = tid >> 4;
    int mTile = blockIdx.x * BM;
    int nTile = blockIdx.y * BN;
    float acc[4][4] = {};

    for (int k0 = 0; k0 < KTOT; k0 += BK) {
        // stage A (transposed into As[k][m]); row = tid/4, kc = (tid%4)*8
        {
            int row = tid >> 2;
            int kc = (tid & 3) * 8;
            int m = mTile + row;
            float vr[8];
            if (m < NN) {
                int kg = k0 + kc;
                const float* src;
                float scale = 1.f;
                if (SPLIT) {
                    if (kg < HD) {
                        src = A1 + (size_t)m * HD + kg;
                    } else {
                        src = A2 + (size_t)m * HD + (kg - HD);
                        scale = (float)deg[m];
                    }
                } else {
                    src = A1 + (size_t)m * HD + kg;
                }
                float4 u0 = *reinterpret_cast<const float4*>(src);
                float4 u1 = *reinterpret_cast<const float4*>(src + 4);
                vr[0] = u0.x * scale; vr[1] = u0.y * scale;
                vr[2] = u0.z * scale; vr[3] = u0.w * scale;
                vr[4] = u1.x * scale; vr[5] = u1.y * scale;
                vr[6] = u1.z * scale; vr[7] = u1.w * scale;
            } else {
#pragma unroll
                for (int i = 0; i < 8; i++) vr[i] = 0.f;
            }
#pragma unroll
            for (int i = 0; i < 8; i++) As[kc + i][row] = vr[i];
        }
        // stage B: kk = tid/8, nn = (tid%8)*8
        {
            int kk = tid >> 3;
            int nn = (tid & 7) * 8;
            const float* src = B + (size_t)(k0 + kk) * G3 + nTile + nn;
            float4 u0 = *reinterpret_cast<const float4*>(src);
            float4 u1 = *reinterpret_cast<const float4*>(src + 4);
            *reinterpret_cast<float4*>(&Bs[kk][nn]) = u0;
            *reinterpret_cast<float4*>(&Bs[kk][nn + 4]) = u1;
        }
        __syncthreads();
#pragma unroll
        for (int k = 0; k < BK; k++) {
            float4 a = *reinterpret_cast<const float4*>(&As[k][ty * 4]);
            float4 b = *reinterpret_cast<const float4*>(&Bs[k][tx * 4]);
            float av[4] = {a.x, a.y, a.z, a.w};
            float bv[4] = {b.x, b.y, b.z, b.w};
#pragma unroll
            for (int i = 0; i < 4; i++)
#pragma unroll
                for (int j = 0; j < 4; j++) acc[i][j] += av[i] * bv[j];
        }
        __syncthreads();
    }

    int n0 = nTile + tx * 4;
#pragma unroll
    for (int i = 0; i < 4; i++) {
        int m = mTile + ty * 4 + i;
        if (m >= NN) continue;
        float dv = SPLIT ? (float)deg[m] : 0.f;
        float4 o;
        float* po = &o.x;
#pragma unroll
        for (int j = 0; j < 4; j++) {
            float v = acc[i][j] + bias[n0 + j];
            if (SPLIT) v += dv * c3[n0 + j];
            po[j] = v;
        }
        *reinterpret_cast<float4*>(C + (size_t)m * G3 + n0) = o;
    }
}

// ---------------- GRU elementwise ----------------
__global__ void k_gru(const float* __restrict__ U, const float* __restrict__ GH,
                      const float* __restrict__ hcur, const int* __restrict__ deg,
                      float* __restrict__ hout) {
    int idx = blockIdx.x * blockDim.x + threadIdx.x;
    if (idx >= NN * HD) return;
    int v = idx >> 7;
    int d = idx & 127;
    const float* u = U + (size_t)v * G3;
    const float* g = GH + (size_t)v * G3;
    float ur = u[d], uz = u[HD + d], un = u[2 * HD + d];
    float gr = g[d], gz = g[HD + d], gn = g[2 * HD + d];
    float hv = hcur[idx];
    float r = 1.f / (1.f + expf(-(ur + gr)));
    float z = 1.f / (1.f + expf(-(uz + gz)));
    float n = tanhf(un + r * gn);
    float hnew = (1.f - z) * n + z * hv;
    hout[idx] = (deg[v] > 0) ? hnew : hv;
}

extern "C" void kernel_launch(void* const* d_in, const int* in_sizes, int n_in,
                              void* d_out, int out_size, void* d_ws, size_t ws_size,
                              hipStream_t stream) {
    const float* h_in  = (const float*)d_in[0];
    const int*   edges = (const int*)d_in[1];
    const float* W_msg = (const float*)d_in[2];
    const float* b_msg = (const float*)d_in[3];
    const float* W_ih  = (const float*)d_in[4];
    const float* W_hh  = (const float*)d_in[5];
    const float* b_ih  = (const float*)d_in[6];
    const float* b_hh  = (const float*)d_in[7];
    float* out = (float*)d_out;

    char* p = (char*)d_ws;
    auto alloc = [&](size_t bytes) {
        void* r = (void*)p;
        p += (bytes + 255) / 256 * 256;
        return r;
    };
    int*   deg     = (int*)alloc((size_t)NN * 4);
    int*   off     = (int*)alloc((size_t)(NN + 1) * 4);
    int*   cur     = (int*)alloc((size_t)NN * 4);
    int*   csr_src = (int*)alloc((size_t)NE * 4);
    float* sbuf    = (float*)alloc((size_t)NN * HD * 4);
    float* h1      = (float*)alloc((size_t)NN * HD * 4);
    float* U       = (float*)alloc((size_t)NN * G3 * 4);
    float* GH      = (float*)alloc((size_t)NN * G3 * 4);
    float* B1      = (float*)alloc((size_t)2 * K2 * G3 * 4);
    float* B2      = (float*)alloc((size_t)2 * HD * G3 * 4);
    float* c3      = (float*)alloc((size_t)2 * G3 * 4);

    hipMemsetAsync(deg, 0, (size_t)NN * 4, stream);
    k_deg<<<(NE + 255) / 256, 256, 0, stream>>>(edges, deg);
    k_scan<<<1, 1024, 0, stream>>>(deg, off, cur);
    k_fill<<<(NE + 255) / 256, 256, 0, stream>>>(edges, cur, csr_src);
    k_comb1<<<(2 * K2 * G3 + 255) / 256, 256, 0, stream>>>(W_ih, W_msg, B1);
    k_comb2<<<(2 * HD * G3 + 255) / 256, 256, 0, stream>>>(W_hh, B2);
    k_comb3<<<(2 * G3 + 255) / 256, 256, 0, stream>>>(W_ih, b_msg, c3);

    dim3 gemm_grid((NN + 63) / 64, G3 / 64);
    const float* hcur = h_in;
    for (int t = 0; t < 2; t++) {
        float* hnext = (t == 0) ? h1 : out;
        k_agg<<<(NN * 64) / 256, 256, 0, stream>>>(hcur, off, deg, csr_src, sbuf);
        k_gemm<K2, true><<<gemm_grid, 256, 0, stream>>>(
            sbuf, hcur, deg, B1 + (size_t)t * K2 * G3, b_ih + t * G3, c3 + t * G3, U);
        k_gemm<HD, false><<<gemm_grid, 256, 0, stream>>>(
            hcur, nullptr, deg, B2 + (size_t)t * HD * G3, b_hh + t * G3, nullptr, GH);
        k_gru<<<(NN * HD + 255) / 256, 256, 0, stream>>>(U, GH, hcur, deg, hnext);
        hcur = hnext;
    }
}

// Round 3
// 577.568 us; speedup vs baseline: 1.5246x; 1.5246x over previous
//
#include <hip/hip_runtime.h>
#include <hip/hip_bf16.h>

#define NN 50000
#define NE 800000
#define HD 128
#define G3 384   // 3*H
#define K2 256   // 2*H

typedef short s16x8 __attribute__((ext_vector_type(8)));
typedef float f32x4 __attribute__((ext_vector_type(4)));

static __device__ __forceinline__ ushort f2b(float f) {
    __hip_bfloat16 b = __float2bfloat16(f);
    return *(ushort*)&b;
}
static __device__ __forceinline__ float b2f(ushort u) {
    return __uint_as_float(((uint)u) << 16);
}

// ---------------- CSR build ----------------
__global__ void k_deg(const int* __restrict__ edges, int* __restrict__ deg) {
    int e = blockIdx.x * blockDim.x + threadIdx.x;
    if (e < NE) atomicAdd(&deg[edges[2 * e + 1]], 1);
}

// off[v] = atomic reservation of deg[v] slots (CSR order irrelevant for a sum)
__global__ void k_off(const int* __restrict__ deg, int* __restrict__ off,
                      int* __restrict__ cur, int* __restrict__ counter) {
    int v = blockIdx.x * blockDim.x + threadIdx.x;
    if (v < NN) {
        int o = atomicAdd(counter, deg[v]);
        off[v] = o;
        cur[v] = o;
    }
}

__global__ void k_fill(const int* __restrict__ edges, int* __restrict__ cur,
                       int* __restrict__ csr_src) {
    int e = blockIdx.x * blockDim.x + threadIdx.x;
    if (e < NE) {
        int s = edges[2 * e];
        int d = edges[2 * e + 1];
        int pos = atomicAdd(&cur[d], 1);
        csr_src[pos] = s;
    }
}

// ---------------- combined weights (f32) ----------------
// B1[t][k][n] = sum_j W_ih[t][n][j] * W_msg[t][j][k]   (k<256, n<384)
__global__ void k_comb1(const float* __restrict__ W_ih, const float* __restrict__ W_msg,
                        float* __restrict__ B1) {
    int idx = blockIdx.x * blockDim.x + threadIdx.x;
    if (idx >= 2 * K2 * G3) return;
    int k = idx % K2;
    int n = (idx / K2) % G3;
    int t = idx / (K2 * G3);
    const float* wi = W_ih + ((size_t)t * G3 + n) * K2;
    const float* wm = W_msg + (size_t)t * K2 * K2;
    float acc = 0.f;
#pragma unroll 8
    for (int j = 0; j < K2; j++) acc += wi[j] * wm[(size_t)j * K2 + k];
    B1[((size_t)t * K2 + k) * G3 + n] = acc;
}

// c3[t][n] = sum_j W_ih[t][n][j] * b_msg[t][j]
__global__ void k_comb3(const float* __restrict__ W_ih, const float* __restrict__ b_msg,
                        float* __restrict__ c3) {
    int idx = blockIdx.x * blockDim.x + threadIdx.x;
    if (idx >= 2 * G3) return;
    int n = idx % G3;
    int t = idx / G3;
    const float* wi = W_ih + ((size_t)t * G3 + n) * K2;
    const float* bm = b_msg + t * K2;
    float acc = 0.f;
#pragma unroll 8
    for (int j = 0; j < K2; j++) acc += wi[j] * bm[j];
    c3[idx] = acc;
}

// ---------------- pack B into MFMA fragment order (bf16) ----------------
// Bc[t][dhalf][slot(192)][lane(64)][e(8)]
// slot<48:          kb=slot/12, n=slot%12, mode C1     (A k-range: s slab)
// slot in [48,192): rel=slot-48, kb=rel/36, j=rel%36:
//   j<12 : n=j,    C2_hi   (A: h_hi slab; reused for h_lo slab in phase 3)
//   j<24 : n=j-12, W_hh
//   else : n=j-24, C2_lo
// frag element: k = kb*32 + (lane>>4)*8 + e  (within-slab 0..127)
// out col: g=n>>2, dn=n&3, d = dhalf*64 + dn*16 + (lane&15)
__global__ void k_pack2(const float* __restrict__ B1, const float* __restrict__ W_hh,
                        ushort* __restrict__ Bc) {
    int idx = blockIdx.x * blockDim.x + threadIdx.x;
    if (idx >= 2 * 2 * 192 * 64) return;
    int lane = idx & 63;
    int slot = (idx >> 6) % 192;
    int dhalf = ((idx >> 6) / 192) % 2;
    int t = idx / (64 * 192 * 2);
    int kb, n, mode;  // 0=C1, 1=C2_hi, 2=W_hh, 3=C2_lo
    if (slot < 48) {
        kb = slot / 12; n = slot % 12; mode = 0;
    } else {
        int rel = slot - 48;
        kb = rel / 36;
        int j = rel % 36;
        if (j < 12)      { n = j;      mode = 1; }
        else if (j < 24) { n = j - 12; mode = 2; }
        else             { n = j - 24; mode = 3; }
    }
    int g = n >> 2, dn = n & 3;
    int d = dhalf * 64 + dn * 16 + (lane & 15);
    int kbase = kb * 32 + (lane >> 4) * 8;
    ushort* dst = Bc + (size_t)idx * 8;
#pragma unroll
    for (int e = 0; e < 8; e++) {
        int k = kbase + e;  // 0..127 within slab
        float v;
        if (mode == 0) {
            v = B1[((size_t)t * K2 + k) * G3 + g * 128 + d];
        } else if (mode == 2) {
            v = W_hh[((size_t)t * G3 + g * 128 + d) * HD + k];
        } else {
            float full = B1[((size_t)t * K2 + 128 + k) * G3 + g * 128 + d];
            if (mode == 1) v = full;                      // f2b gives hi
            else           v = full - b2f(f2b(full));     // lo residual
        }
        dst[e] = f2b(v);
    }
}

// bias packs, each [t][dhalf][12][16]
__global__ void k_packbias2(const float* __restrict__ b_ih, const float* __restrict__ b_hh,
                            const float* __restrict__ c3,
                            float* __restrict__ bih_p, float* __restrict__ bhh_p,
                            float* __restrict__ c3_p) {
    int idx = blockIdx.x * blockDim.x + threadIdx.x;
    if (idx >= 2 * 2 * 12 * 16) return;
    int c = idx & 15;
    int n = (idx >> 4) % 12;
    int dhalf = ((idx >> 4) / 12) % 2;
    int t = idx / (16 * 12 * 2);
    int g = n >> 2, dn = n & 3;
    int d = dhalf * 64 + dn * 16 + c;
    bih_p[idx] = b_ih[t * G3 + g * 128 + d];
    bhh_p[idx] = b_hh[t * G3 + g * 128 + d];
    c3_p[idx]  = c3[t * G3 + g * 128 + d];
}

// ---------------- h f32 -> bf16 (for gathers) ----------------
__global__ void k_h2b(const float* __restrict__ h, ushort* __restrict__ hb) {
    int i = blockIdx.x * blockDim.x + threadIdx.x;
    if (i >= NN * HD / 4) return;
    float4 v = reinterpret_cast<const float4*>(h)[i];
    ushort4 o;
    o.x = f2b(v.x); o.y = f2b(v.y); o.z = f2b(v.z); o.w = f2b(v.w);
    reinterpret_cast<ushort4*>(hb)[i] = o;
}

// ---------------- prep: A rows [s | h_hi | h_lo] bf16 ----------------
__global__ void k_prep(const ushort* __restrict__ hb, const float* __restrict__ hf,
                       const int* __restrict__ off, const int* __restrict__ deg,
                       const int* __restrict__ csr, ushort* __restrict__ Abf) {
    int wv = (blockIdx.x * blockDim.x + threadIdx.x) >> 6;
    int lane = threadIdx.x & 63;
    if (wv >= NN) return;
    int st = off[wv];
    int dg = deg[wv];
    float a0 = 0.f, a1 = 0.f;
    for (int j = 0; j < dg; j++) {
        int s = csr[st + j];
        uint v = *reinterpret_cast<const uint*>(hb + (size_t)s * HD + lane * 2);
        a0 += b2f((ushort)(v & 0xffff));
        a1 += b2f((ushort)(v >> 16));
    }
    uint* arow = reinterpret_cast<uint*>(Abf + (size_t)wv * G3);
    arow[lane] = (uint)f2b(a0) | ((uint)f2b(a1) << 16);
    float2 hv = *reinterpret_cast<const float2*>(hf + (size_t)wv * HD + lane * 2);
    ushort h0 = f2b(hv.x), h1 = f2b(hv.y);
    ushort l0 = f2b(hv.x - b2f(h0)), l1 = f2b(hv.y - b2f(h1));
    arow[64 + lane]  = (uint)h0 | ((uint)h1 << 16);
    arow[128 + lane] = (uint)l0 | ((uint)l1 << 16);
}

// ---------------- fused MFMA GEMM + GRU ----------------
// grid (782, 2); block 256 (4 waves); wave owns 16 rows x its d-half.
// accA = C1*s ; accB = C2*h (split-precision) ; accC = W_hh*h_hi
__global__ __launch_bounds__(256) void k_fused(
    const ushort* __restrict__ Abf,     // [NN][384] bf16
    const ushort* __restrict__ Bc_t,    // [dhalf][192][512] bf16 (this t)
    const float* __restrict__ bih_t,    // [dhalf][12][16]
    const float* __restrict__ bhh_t,
    const float* __restrict__ c3_t,
    const int* __restrict__ deg,
    const float* __restrict__ hcur,     // [NN][128] f32
    float* __restrict__ hout,           // [NN][128] f32
    ushort* __restrict__ hb_out)        // [NN][128] bf16
{
    int m0 = blockIdx.x * 64;
    int dhalf = blockIdx.y;
    int w = threadIdx.x >> 6;
    int lane = threadIdx.x & 63;
    int lhi = lane >> 4;
    int col = lane & 15;
    int rowbase = m0 + w * 16;

    int ar = rowbase + col;
    int armin = ar < NN ? ar : NN - 1;
    const s16x8* ap = reinterpret_cast<const s16x8*>(Abf + (size_t)armin * G3);
    const s16x8* bp = reinterpret_cast<const s16x8*>(Bc_t) + (size_t)dhalf * 192 * 64;

    f32x4 accA[12], accB[12], accC[12];
#pragma unroll
    for (int i = 0; i < 12; i++) {
        accA[i] = f32x4{0.f, 0.f, 0.f, 0.f};
        accB[i] = f32x4{0.f, 0.f, 0.f, 0.f};
        accC[i] = f32x4{0.f, 0.f, 0.f, 0.f};
    }

    // phase 1: C1 * s   (A elems 0..127)
#pragma unroll
    for (int kb = 0; kb < 4; kb++) {
        s16x8 a = ap[kb * 4 + lhi];
#pragma unroll
        for (int n = 0; n < 12; n++)
            accA[n] = __builtin_amdgcn_mfma_f32_16x16x32_bf16(
                a, bp[((size_t)(kb * 12 + n)) * 64 + lane], accA[n], 0, 0, 0);
    }
    // phase 2: h_hi slab (A elems 128..255): C2_hi, W_hh, C2_lo
#pragma unroll
    for (int kb = 0; kb < 4; kb++) {
        s16x8 a = ap[16 + kb * 4 + lhi];
        int base = 48 + kb * 36;
#pragma unroll
        for (int n = 0; n < 12; n++)
            accB[n] = __builtin_amdgcn_mfma_f32_16x16x32_bf16(
                a, bp[((size_t)(base + n)) * 64 + lane], accB[n], 0, 0, 0);
#pragma unroll
        for (int n = 0; n < 12; n++)
            accC[n] = __builtin_amdgcn_mfma_f32_16x16x32_bf16(
                a, bp[((size_t)(base + 12 + n)) * 64 + lane], accC[n], 0, 0, 0);
#pragma unroll
        for (int n = 0; n < 12; n++)
            accB[n] = __builtin_amdgcn_mfma_f32_16x16x32_bf16(
                a, bp[((size_t)(base + 24 + n)) * 64 + lane], accB[n], 0, 0, 0);
    }
    // phase 3: h_lo slab (A elems 256..383) * C2_hi
#pragma unroll
    for (int kb = 0; kb < 4; kb++) {
        s16x8 a = ap[32 + kb * 4 + lhi];
        int base = 48 + kb * 36;
#pragma unroll
        for (int n = 0; n < 12; n++)
            accB[n] = __builtin_amdgcn_mfma_f32_16x16x32_bf16(
                a, bp[((size_t)(base + n)) * 64 + lane], accB[n], 0, 0, 0);
    }

    // epilogue: GRU in-register
    float bih[3][4], bhh[3][4], c3v[3][4];
#pragma unroll
    for (int g = 0; g < 3; g++)
#pragma unroll
        for (int dn = 0; dn < 4; dn++) {
            int o = (dhalf * 12 + g * 4 + dn) * 16 + col;
            bih[g][dn] = bih_t[o];
            bhh[g][dn] = bhh_t[o];
            c3v[g][dn] = c3_t[o];
        }

    int rbase0 = rowbase + (lhi << 2);
#pragma unroll
    for (int r = 0; r < 4; r++) {
        int m = rbase0 + r;
        bool wr = m < NN;
        int mm = wr ? m : 0;
        int dgi = deg[mm];
        float dgf = (float)dgi;
#pragma unroll
        for (int dn = 0; dn < 4; dn++) {
            int d = (dhalf << 6) + (dn << 4) + col;
            float hv = hcur[(size_t)mm * HD + d];
            float ir  = accA[dn][r]     + dgf * (accB[dn][r]     + c3v[0][dn]) + bih[0][dn];
            float iz  = accA[4 + dn][r] + dgf * (accB[4 + dn][r] + c3v[1][dn]) + bih[1][dn];
            float in_ = accA[8 + dn][r] + dgf * (accB[8 + dn][r] + c3v[2][dn]) + bih[2][dn];
            float hr = accC[dn][r]     + bhh[0][dn];
            float hz = accC[4 + dn][r] + bhh[1][dn];
            float hn = accC[8 + dn][r] + bhh[2][dn];
            float rg = 1.f / (1.f + expf(-(ir + hr)));
            float zg = 1.f / (1.f + expf(-(iz + hz)));
            float ng = tanhf(in_ + rg * hn);
            float hnew = (1.f - zg) * ng + zg * hv;
            float res = (dgi > 0) ? hnew : hv;
            if (wr) {
                hout[(size_t)m * HD + d] = res;
                hb_out[(size_t)m * HD + d] = f2b(res);
            }
        }
    }
}

extern "C" void kernel_launch(void* const* d_in, const int* in_sizes, int n_in,
                              void* d_out, int out_size, void* d_ws, size_t ws_size,
                              hipStream_t stream) {
    const float* h_in  = (const float*)d_in[0];
    const int*   edges = (const int*)d_in[1];
    const float* W_msg = (const float*)d_in[2];
    const float* b_msg = (const float*)d_in[3];
    const float* W_ih  = (const float*)d_in[4];
    const float* W_hh  = (const float*)d_in[5];
    const float* b_ih  = (const float*)d_in[6];
    const float* b_hh  = (const float*)d_in[7];
    float* out = (float*)d_out;

    char* p = (char*)d_ws;
    auto alloc = [&](size_t bytes) {
        void* r = (void*)p;
        p += (bytes + 255) / 256 * 256;
        return r;
    };
    int*    deg     = (int*)alloc((size_t)(NN + 1) * 4);  // +1: counter
    int*    off     = (int*)alloc((size_t)NN * 4);
    int*    cur     = (int*)alloc((size_t)NN * 4);
    int*    csr_src = (int*)alloc((size_t)NE * 4);
    float*  B1      = (float*)alloc((size_t)2 * K2 * G3 * 4);
    float*  c3      = (float*)alloc((size_t)2 * G3 * 4);
    ushort* Bc      = (ushort*)alloc((size_t)2 * 2 * 192 * 512 * 2);
    float*  bih_p   = (float*)alloc((size_t)2 * 2 * 12 * 16 * 4);
    float*  bhh_p   = (float*)alloc((size_t)2 * 2 * 12 * 16 * 4);
    float*  c3_p    = (float*)alloc((size_t)2 * 2 * 12 * 16 * 4);
    ushort* hb0     = (ushort*)alloc((size_t)NN * HD * 2);
    ushort* hb1     = (ushort*)alloc((size_t)NN * HD * 2);
    ushort* hb2     = (ushort*)alloc((size_t)NN * HD * 2);
    ushort* Abf     = (ushort*)alloc((size_t)NN * G3 * 2);
    float*  h1      = (float*)alloc((size_t)NN * HD * 4);
    int*    counter = deg + NN;

    hipMemsetAsync(deg, 0, (size_t)(NN + 1) * 4, stream);
    k_deg<<<(NE + 255) / 256, 256, 0, stream>>>(edges, deg);
    k_off<<<(NN + 255) / 256, 256, 0, stream>>>(deg, off, cur, counter);
    k_fill<<<(NE + 255) / 256, 256, 0, stream>>>(edges, cur, csr_src);
    k_comb1<<<(2 * K2 * G3 + 255) / 256, 256, 0, stream>>>(W_ih, W_msg, B1);
    k_comb3<<<(2 * G3 + 255) / 256, 256, 0, stream>>>(W_ih, b_msg, c3);
    k_pack2<<<(2 * 2 * 192 * 64 + 255) / 256, 256, 0, stream>>>(B1, W_hh, Bc);
    k_packbias2<<<(2 * 2 * 12 * 16 + 255) / 256, 256, 0, stream>>>(b_ih, b_hh, c3,
                                                                   bih_p, bhh_p, c3_p);
    k_h2b<<<(NN * HD / 4 + 255) / 256, 256, 0, stream>>>(h_in, hb0);

    dim3 fgrid((NN + 63) / 64, 2);
    const size_t BcT = (size_t)2 * 192 * 512;
    const size_t biasT = (size_t)2 * 12 * 16;

    // step 0
    k_prep<<<(NN * 64 + 255) / 256, 256, 0, stream>>>(hb0, h_in, off, deg, csr_src, Abf);
    k_fused<<<fgrid, 256, 0, stream>>>(Abf, Bc, bih_p, bhh_p, c3_p, deg, h_in, h1, hb1);
    // step 1
    k_prep<<<(NN * 64 + 255) / 256, 256, 0, stream>>>(hb1, h1, off, deg, csr_src, Abf);
    k_fused<<<fgrid, 256, 0, stream>>>(Abf, Bc + BcT, bih_p + biasT, bhh_p + biasT,
                                       c3_p + biasT, deg, h1, out, hb2);
}

// Round 4
// 531.080 us; speedup vs baseline: 1.6580x; 1.0875x over previous
//
#include <hip/hip_runtime.h>
#include <hip/hip_bf16.h>

#define NN 50000
#define NE 800000
#define HD 128
#define G3 384   // 3*H
#define K2 256   // 2*H

typedef short s16x8 __attribute__((ext_vector_type(8)));
typedef float f32x4 __attribute__((ext_vector_type(4)));

static __device__ __forceinline__ ushort f2b(float f) {
    __hip_bfloat16 b = __float2bfloat16(f);
    return *(ushort*)&b;
}
static __device__ __forceinline__ float b2f(ushort u) {
    return __uint_as_float(((uint)u) << 16);
}

// ---------------- CSR build ----------------
__global__ void k_deg(const int* __restrict__ edges, int* __restrict__ deg) {
    int e = blockIdx.x * blockDim.x + threadIdx.x;
    if (e < NE) atomicAdd(&deg[edges[2 * e + 1]], 1);
}

__global__ void k_off(const int* __restrict__ deg, int* __restrict__ off,
                      int* __restrict__ cur, int* __restrict__ counter) {
    int v = blockIdx.x * blockDim.x + threadIdx.x;
    if (v < NN) {
        int o = atomicAdd(counter, deg[v]);
        off[v] = o;
        cur[v] = o;
    }
}

__global__ void k_fill(const int* __restrict__ edges, int* __restrict__ cur,
                       int* __restrict__ csr_src) {
    int e = blockIdx.x * blockDim.x + threadIdx.x;
    if (e < NE) {
        int s = edges[2 * e];
        int d = edges[2 * e + 1];
        int pos = atomicAdd(&cur[d], 1);
        csr_src[pos] = s;
    }
}

// ---------------- combined weights (f32) ----------------
// B1[t][k][n] = sum_j W_ih[t][n][j] * W_msg[t][j][k]   (k<256, n<384)
__global__ void k_comb1(const float* __restrict__ W_ih, const float* __restrict__ W_msg,
                        float* __restrict__ B1) {
    int idx = blockIdx.x * blockDim.x + threadIdx.x;
    if (idx >= 2 * K2 * G3) return;
    int k = idx % K2;
    int n = (idx / K2) % G3;
    int t = idx / (K2 * G3);
    const float* wi = W_ih + ((size_t)t * G3 + n) * K2;
    const float* wm = W_msg + (size_t)t * K2 * K2;
    float acc = 0.f;
#pragma unroll 8
    for (int j = 0; j < K2; j++) acc += wi[j] * wm[(size_t)j * K2 + k];
    B1[((size_t)t * K2 + k) * G3 + n] = acc;
}

// c3[t][n] = sum_j W_ih[t][n][j] * b_msg[t][j]
__global__ void k_comb3(const float* __restrict__ W_ih, const float* __restrict__ b_msg,
                        float* __restrict__ c3) {
    int idx = blockIdx.x * blockDim.x + threadIdx.x;
    if (idx >= 2 * G3) return;
    int n = idx % G3;
    int t = idx / G3;
    const float* wi = W_ih + ((size_t)t * G3 + n) * K2;
    const float* bm = b_msg + t * K2;
    float acc = 0.f;
#pragma unroll 8
    for (int j = 0; j < K2; j++) acc += wi[j] * bm[j];
    c3[idx] = acc;
}

// ---------------- pack B into linear MFMA stream (bf16) ----------------
// Bc[t][dhalf][slot(192)][lane(64)][e(8)]
// group g = slot/12, n = slot%12.
//   g<4            : C1,     kb=g
//   else r=(g-4)%3 : r=0 C2_hi, r=1 W_hh, r=2 C2_lo ; kb=(g-4)/3
// out col: gate=n>>2, dn=n&3, d = dhalf*64 + dn*16 + (lane&15)
// frag k (within 128-slab) = kb*32 + (lane>>4)*8 + e
__global__ void k_pack3(const float* __restrict__ B1, const float* __restrict__ W_hh,
                        ushort* __restrict__ Bc) {
    int idx = blockIdx.x * blockDim.x + threadIdx.x;
    if (idx >= 2 * 2 * 192 * 64) return;
    int lane = idx & 63;
    int slot = (idx >> 6) % 192;
    int dhalf = ((idx >> 6) / 192) % 2;
    int t = idx / (64 * 192 * 2);
    int g = slot / 12, n = slot % 12;
    int mode, kb;  // 0=C1, 1=C2_hi, 2=W_hh, 3=C2_lo
    if (g < 4) { mode = 0; kb = g; }
    else {
        int q = (g - 4) / 3, r = (g - 4) % 3;
        kb = q;
        mode = (r == 0) ? 1 : ((r == 1) ? 2 : 3);
    }
    int gate = n >> 2, dn = n & 3;
    int d = dhalf * 64 + dn * 16 + (lane & 15);
    int kbase = kb * 32 + (lane >> 4) * 8;
    ushort* dst = Bc + (size_t)idx * 8;
#pragma unroll
    for (int e = 0; e < 8; e++) {
        int k = kbase + e;  // 0..127 within slab
        float v;
        if (mode == 0) {
            v = B1[((size_t)t * K2 + k) * G3 + gate * 128 + d];
        } else if (mode == 2) {
            v = W_hh[((size_t)t * G3 + gate * 128 + d) * HD + k];
        } else {
            float full = B1[((size_t)t * K2 + 128 + k) * G3 + gate * 128 + d];
            v = (mode == 1) ? full : (full - b2f(f2b(full)));
        }
        dst[e] = f2b(v);
    }
}

// bias packs, each [t][dhalf][12][16]
__global__ void k_packbias2(const float* __restrict__ b_ih, const float* __restrict__ b_hh,
                            const float* __restrict__ c3,
                            float* __restrict__ bih_p, float* __restrict__ bhh_p,
                            float* __restrict__ c3_p) {
    int idx = blockIdx.x * blockDim.x + threadIdx.x;
    if (idx >= 2 * 2 * 12 * 16) return;
    int c = idx & 15;
    int n = (idx >> 4) % 12;
    int dhalf = ((idx >> 4) / 12) % 2;
    int t = idx / (16 * 12 * 2);
    int g = n >> 2, dn = n & 3;
    int d = dhalf * 64 + dn * 16 + c;
    bih_p[idx] = b_ih[t * G3 + g * 128 + d];
    bhh_p[idx] = b_hh[t * G3 + g * 128 + d];
    c3_p[idx]  = c3[t * G3 + g * 128 + d];
}

// ---------------- h f32 -> bf16 (for gathers) ----------------
__global__ void k_h2b(const float* __restrict__ h, ushort* __restrict__ hb) {
    int i = blockIdx.x * blockDim.x + threadIdx.x;
    if (i >= NN * HD / 4) return;
    float4 v = reinterpret_cast<const float4*>(h)[i];
    ushort4 o;
    o.x = f2b(v.x); o.y = f2b(v.y); o.z = f2b(v.z); o.w = f2b(v.w);
    reinterpret_cast<ushort4*>(hb)[i] = o;
}

// ---------------- prep: A rows [s | (deg*h)_hi | (deg*h)_lo | h_hi] bf16 ----------------
__global__ void k_prep(const ushort* __restrict__ hb, const float* __restrict__ hf,
                       const int* __restrict__ off, const int* __restrict__ deg,
                       const int* __restrict__ csr, ushort* __restrict__ Abf) {
    int wv = (blockIdx.x * blockDim.x + threadIdx.x) >> 6;
    int lane = threadIdx.x & 63;
    if (wv >= NN) return;
    int st = off[wv];
    int dg = deg[wv];
    float a0 = 0.f, a1 = 0.f;
    int j = 0;
    for (; j + 4 <= dg; j += 4) {
        int s0 = csr[st + j], s1 = csr[st + j + 1];
        int s2 = csr[st + j + 2], s3 = csr[st + j + 3];
        uint v0 = *reinterpret_cast<const uint*>(hb + (size_t)s0 * HD + lane * 2);
        uint v1 = *reinterpret_cast<const uint*>(hb + (size_t)s1 * HD + lane * 2);
        uint v2 = *reinterpret_cast<const uint*>(hb + (size_t)s2 * HD + lane * 2);
        uint v3 = *reinterpret_cast<const uint*>(hb + (size_t)s3 * HD + lane * 2);
        a0 += b2f((ushort)(v0 & 0xffff)) + b2f((ushort)(v1 & 0xffff)) +
              b2f((ushort)(v2 & 0xffff)) + b2f((ushort)(v3 & 0xffff));
        a1 += b2f((ushort)(v0 >> 16)) + b2f((ushort)(v1 >> 16)) +
              b2f((ushort)(v2 >> 16)) + b2f((ushort)(v3 >> 16));
    }
    for (; j < dg; j++) {
        int s = csr[st + j];
        uint v = *reinterpret_cast<const uint*>(hb + (size_t)s * HD + lane * 2);
        a0 += b2f((ushort)(v & 0xffff));
        a1 += b2f((ushort)(v >> 16));
    }
    uint* arow = reinterpret_cast<uint*>(Abf + (size_t)wv * 512);
    arow[lane] = (uint)f2b(a0) | ((uint)f2b(a1) << 16);
    float2 hv = *reinterpret_cast<const float2*>(hf + (size_t)wv * HD + lane * 2);
    float dgf = (float)dg;
    float dh0 = dgf * hv.x, dh1 = dgf * hv.y;
    ushort p0 = f2b(dh0), p1 = f2b(dh1);
    ushort l0 = f2b(dh0 - b2f(p0)), l1 = f2b(dh1 - b2f(p1));
    arow[64 + lane]  = (uint)p0 | ((uint)p1 << 16);
    arow[128 + lane] = (uint)l0 | ((uint)l1 << 16);
    arow[192 + lane] = (uint)f2b(hv.x) | ((uint)f2b(hv.y) << 16);
}

// ---------------- fused MFMA GEMM + GRU, LDS-staged B ----------------
// grid (782, 2); block 256 (4 waves); wave owns 16 rows x its d-half.
// B streamed through LDS in 8 double-buffered chunks of 24 slots (24KB).
#define LOADN(c)                                                        \
    _Pragma("unroll") for (int i = 0; i < 6; i++)                       \
        st[i] = gB4[(size_t)(c) * 1536 + i * 256 + tid];

#define WRITEN(c)                                                       \
    _Pragma("unroll") for (int i = 0; i < 6; i++)                       \
        *reinterpret_cast<uint4*>(&Bs[(c) & 1][(size_t)(i * 256 + tid) * 8]) = st[i];

#define GROUP(p, a1off, dual, a2off, ACC)                               \
    do {                                                                \
        s16x8 a1 = ap[(a1off) + lhi];                                   \
        s16x8 a2 = (dual) ? ap[(a2off) + lhi] : a1;                     \
        _Pragma("unroll") for (int n = 0; n < 12; n++) {                \
            s16x8 b = *reinterpret_cast<const s16x8*>(                  \
                &bufc[((p) * 12 + n) * 512 + lane * 8]);                \
            ACC[n] = __builtin_amdgcn_mfma_f32_16x16x32_bf16(a1, b, ACC[n], 0, 0, 0); \
            if (dual)                                                   \
                ACC[n] = __builtin_amdgcn_mfma_f32_16x16x32_bf16(a2, b, ACC[n], 0, 0, 0); \
        }                                                               \
    } while (0)

#define CHUNK(c, ...)                                                   \
    {                                                                   \
        if ((c) < 7) { LOADN((c) + 1); }                                \
        const ushort* bufc = &Bs[(c) & 1][0];                           \
        __VA_ARGS__                                                     \
        __syncthreads();                                                \
        if ((c) < 7) { WRITEN((c) + 1); }                               \
        __syncthreads();                                                \
    }

__global__ __launch_bounds__(256, 2) void k_fused(
    const ushort* __restrict__ Abf,     // [NN][512] bf16
    const ushort* __restrict__ Bc_t,    // [dhalf][192][512] bf16 (this t)
    const float* __restrict__ bih_t,    // [dhalf][12][16]
    const float* __restrict__ bhh_t,
    const float* __restrict__ c3_t,
    const int* __restrict__ deg,
    const float* __restrict__ hcur,     // [NN][128] f32
    float* __restrict__ hout,           // [NN][128] f32
    ushort* __restrict__ hb_out)        // [NN][128] bf16
{
    __shared__ __align__(16) ushort Bs[2][24 * 512];

    int tid = threadIdx.x;
    int m0 = blockIdx.x * 64;
    int dhalf = blockIdx.y;
    int w = tid >> 6;
    int lane = tid & 63;
    int lhi = lane >> 4;
    int col = lane & 15;
    int rowbase = m0 + w * 16;

    int ar = rowbase + col;
    int armin = ar < NN ? ar : NN - 1;
    const s16x8* ap = reinterpret_cast<const s16x8*>(Abf + (size_t)armin * 512);
    const uint4* gB4 = reinterpret_cast<const uint4*>(Bc_t) + (size_t)dhalf * 12288;

    f32x4 accI[12], accH[12];
#pragma unroll
    for (int i = 0; i < 12; i++) {
        accI[i] = f32x4{0.f, 0.f, 0.f, 0.f};
        accH[i] = f32x4{0.f, 0.f, 0.f, 0.f};
    }

    uint4 st[6];
    // prologue: stage chunk 0
    LOADN(0);
    WRITEN(0);
    __syncthreads();

    // A-frag s16x8 offsets: s slab 0..15, dh_hi 16..31, dh_lo 32..47, h_hi 48..63
    CHUNK(0, GROUP(0, 0, 0, 0, accI); GROUP(1, 4, 0, 0, accI);)     // C1 k0, C1 k1
    CHUNK(1, GROUP(0, 8, 0, 0, accI); GROUP(1, 12, 0, 0, accI);)    // C1 k2, C1 k3
    CHUNK(2, GROUP(0, 16, 1, 32, accI); GROUP(1, 48, 0, 0, accH);)  // C2hi k0 (dual), Whh k0
    CHUNK(3, GROUP(0, 16, 0, 0, accI); GROUP(1, 20, 1, 36, accI);)  // C2lo k0, C2hi k1 (dual)
    CHUNK(4, GROUP(0, 52, 0, 0, accH); GROUP(1, 20, 0, 0, accI);)   // Whh k1, C2lo k1
    CHUNK(5, GROUP(0, 24, 1, 40, accI); GROUP(1, 56, 0, 0, accH);)  // C2hi k2 (dual), Whh k2
    CHUNK(6, GROUP(0, 24, 0, 0, accI); GROUP(1, 28, 1, 44, accI);)  // C2lo k2, C2hi k3 (dual)
    CHUNK(7, GROUP(0, 60, 0, 0, accH); GROUP(1, 28, 0, 0, accI);)   // Whh k3, C2lo k3

    // epilogue: GRU in-register
    float bih[3][4], bhh[3][4], c3v[3][4];
#pragma unroll
    for (int g = 0; g < 3; g++)
#pragma unroll
        for (int dn = 0; dn < 4; dn++) {
            int o = (dhalf * 12 + g * 4 + dn) * 16 + col;
            bih[g][dn] = bih_t[o];
            bhh[g][dn] = bhh_t[o];
            c3v[g][dn] = c3_t[o];
        }

    int rbase0 = rowbase + (lhi << 2);
#pragma unroll
    for (int r = 0; r < 4; r++) {
        int m = rbase0 + r;
        bool wr = m < NN;
        int mm = wr ? m : 0;
        int dgi = deg[mm];
        float dgf = (float)dgi;
#pragma unroll
        for (int dn = 0; dn < 4; dn++) {
            int d = (dhalf << 6) + (dn << 4) + col;
            float hv = hcur[(size_t)mm * HD + d];
            float ir  = accI[dn][r]     + dgf * c3v[0][dn] + bih[0][dn];
            float iz  = accI[4 + dn][r] + dgf * c3v[1][dn] + bih[1][dn];
            float in_ = accI[8 + dn][r] + dgf * c3v[2][dn] + bih[2][dn];
            float hr = accH[dn][r]     + bhh[0][dn];
            float hz = accH[4 + dn][r] + bhh[1][dn];
            float hn = accH[8 + dn][r] + bhh[2][dn];
            float rg = 1.f / (1.f + expf(-(ir + hr)));
            float zg = 1.f / (1.f + expf(-(iz + hz)));
            float ng = tanhf(in_ + rg * hn);
            float hnew = (1.f - zg) * ng + zg * hv;
            float res = (dgi > 0) ? hnew : hv;
            if (wr) {
                hout[(size_t)m * HD + d] = res;
                hb_out[(size_t)m * HD + d] = f2b(res);
            }
        }
    }
}

extern "C" void kernel_launch(void* const* d_in, const int* in_sizes, int n_in,
                              void* d_out, int out_size, void* d_ws, size_t ws_size,
                              hipStream_t stream) {
    const float* h_in  = (const float*)d_in[0];
    const int*   edges = (const int*)d_in[1];
    const float* W_msg = (const float*)d_in[2];
    const float* b_msg = (const float*)d_in[3];
    const float* W_ih  = (const float*)d_in[4];
    const float* W_hh  = (const float*)d_in[5];
    const float* b_ih  = (const float*)d_in[6];
    const float* b_hh  = (const float*)d_in[7];
    float* out = (float*)d_out;

    char* p = (char*)d_ws;
    auto alloc = [&](size_t bytes) {
        void* r = (void*)p;
        p += (bytes + 255) / 256 * 256;
        return r;
    };
    int*    deg     = (int*)alloc((size_t)(NN + 1) * 4);  // +1: counter
    int*    off     = (int*)alloc((size_t)NN * 4);
    int*    cur     = (int*)alloc((size_t)NN * 4);
    int*    csr_src = (int*)alloc((size_t)NE * 4);
    float*  B1      = (float*)alloc((size_t)2 * K2 * G3 * 4);
    float*  c3      = (float*)alloc((size_t)2 * G3 * 4);
    ushort* Bc      = (ushort*)alloc((size_t)2 * 2 * 192 * 512 * 2);
    float*  bih_p   = (float*)alloc((size_t)2 * 2 * 12 * 16 * 4);
    float*  bhh_p   = (float*)alloc((size_t)2 * 2 * 12 * 16 * 4);
    float*  c3_p    = (float*)alloc((size_t)2 * 2 * 12 * 16 * 4);
    ushort* hb0     = (ushort*)alloc((size_t)NN * HD * 2);
    ushort* hb1     = (ushort*)alloc((size_t)NN * HD * 2);
    ushort* Abf     = (ushort*)alloc((size_t)NN * 512 * 2);
    float*  h1      = (float*)alloc((size_t)NN * HD * 4);
    int*    counter = deg + NN;

    hipMemsetAsync(deg, 0, (size_t)(NN + 1) * 4, stream);
    k_deg<<<(NE + 255) / 256, 256, 0, stream>>>(edges, deg);
    k_off<<<(NN + 255) / 256, 256, 0, stream>>>(deg, off, cur, counter);
    k_fill<<<(NE + 255) / 256, 256, 0, stream>>>(edges, cur, csr_src);
    k_comb1<<<(2 * K2 * G3 + 255) / 256, 256, 0, stream>>>(W_ih, W_msg, B1);
    k_comb3<<<(2 * G3 + 255) / 256, 256, 0, stream>>>(W_ih, b_msg, c3);
    k_pack3<<<(2 * 2 * 192 * 64 + 255) / 256, 256, 0, stream>>>(B1, W_hh, Bc);
    k_packbias2<<<(2 * 2 * 12 * 16 + 255) / 256, 256, 0, stream>>>(b_ih, b_hh, c3,
                                                                   bih_p, bhh_p, c3_p);
    k_h2b<<<(NN * HD / 4 + 255) / 256, 256, 0, stream>>>(h_in, hb0);

    dim3 fgrid((NN + 63) / 64, 2);
    const size_t BcT = (size_t)2 * 192 * 512;   // ushort units per t
    const size_t biasT = (size_t)2 * 12 * 16;

    // step 0
    k_prep<<<(NN * 64 + 255) / 256, 256, 0, stream>>>(hb0, h_in, off, deg, csr_src, Abf);
    k_fused<<<fgrid, 256, 0, stream>>>(Abf, Bc, bih_p, bhh_p, c3_p, deg, h_in, h1, hb1);
    // step 1 (hb_out reuses hb0; it is rebuilt by k_h2b every launch)
    k_prep<<<(NN * 64 + 255) / 256, 256, 0, stream>>>(hb1, h1, off, deg, csr_src, Abf);
    k_fused<<<fgrid, 256, 0, stream>>>(Abf, Bc + BcT, bih_p + biasT, bhh_p + biasT,
                                       c3_p + biasT, deg, h1, out, hb0);
}

// Round 5
// 491.844 us; speedup vs baseline: 1.7903x; 1.0798x over previous
//
#include <hip/hip_runtime.h>
#include <hip/hip_bf16.h>

#define NN 50000
#define NE 800000
#define HD 128
#define G3 384   // 3*H
#define K2 256   // 2*H

typedef short s16x8 __attribute__((ext_vector_type(8)));
typedef float f32x4 __attribute__((ext_vector_type(4)));

static __device__ __forceinline__ ushort f2b(float f) {
    __hip_bfloat16 b = __float2bfloat16(f);
    return *(ushort*)&b;
}
static __device__ __forceinline__ float b2f(ushort u) {
    return __uint_as_float(((uint)u) << 16);
}

static __device__ __forceinline__ void gl_lds16(const void* g, void* l) {
    __builtin_amdgcn_global_load_lds(
        (const __attribute__((address_space(1))) uint*)(uintptr_t)g,
        (__attribute__((address_space(3))) uint*)(uintptr_t)l, 16, 0, 0);
}

// ---------------- CSR build ----------------
__global__ void k_deg(const int* __restrict__ edges, int* __restrict__ deg) {
    int e = blockIdx.x * blockDim.x + threadIdx.x;
    if (e < NE) atomicAdd(&deg[edges[2 * e + 1]], 1);
}

__global__ void k_off(const int* __restrict__ deg, int* __restrict__ off,
                      int* __restrict__ cur, int* __restrict__ counter) {
    int v = blockIdx.x * blockDim.x + threadIdx.x;
    if (v < NN) {
        int o = atomicAdd(counter, deg[v]);
        off[v] = o;
        cur[v] = o;
    }
}

__global__ void k_fill(const int* __restrict__ edges, int* __restrict__ cur,
                       int* __restrict__ csr_src) {
    int e = blockIdx.x * blockDim.x + threadIdx.x;
    if (e < NE) {
        int s = edges[2 * e];
        int d = edges[2 * e + 1];
        int pos = atomicAdd(&cur[d], 1);
        csr_src[pos] = s;
    }
}

// ---------------- combined weights (f32) ----------------
// B1[t][k][n] = sum_j W_ih[t][n][j] * W_msg[t][j][k]   (k<256, n<384)
__global__ void k_comb1(const float* __restrict__ W_ih, const float* __restrict__ W_msg,
                        float* __restrict__ B1) {
    int idx = blockIdx.x * blockDim.x + threadIdx.x;
    if (idx >= 2 * K2 * G3) return;
    int k = idx % K2;
    int n = (idx / K2) % G3;
    int t = idx / (K2 * G3);
    const float* wi = W_ih + ((size_t)t * G3 + n) * K2;
    const float* wm = W_msg + (size_t)t * K2 * K2;
    float acc = 0.f;
#pragma unroll 8
    for (int j = 0; j < K2; j++) acc += wi[j] * wm[(size_t)j * K2 + k];
    B1[((size_t)t * K2 + k) * G3 + n] = acc;
}

// c3[t][n] = sum_j W_ih[t][n][j] * b_msg[t][j]
__global__ void k_comb3(const float* __restrict__ W_ih, const float* __restrict__ b_msg,
                        float* __restrict__ c3) {
    int idx = blockIdx.x * blockDim.x + threadIdx.x;
    if (idx >= 2 * G3) return;
    int n = idx % G3;
    int t = idx / G3;
    const float* wi = W_ih + ((size_t)t * G3 + n) * K2;
    const float* bm = b_msg + t * K2;
    float acc = 0.f;
#pragma unroll 8
    for (int j = 0; j < K2; j++) acc += wi[j] * bm[j];
    c3[idx] = acc;
}

// ---------------- pack B into linear MFMA stream (bf16) ----------------
// Bc[t][dhalf][slot(192)][lane(64)][e(8)]
// group g = slot/12, n = slot%12.
//   g<4            : C1,     kb=g
//   else r=(g-4)%3 : r=0 C2_hi, r=1 W_hh, r=2 C2_lo ; kb=(g-4)/3
// out col: gate=n>>2, dn=n&3, d = dhalf*64 + dn*16 + (lane&15)
// frag k (within 128-slab) = kb*32 + (lane>>4)*8 + e
__global__ void k_pack3(const float* __restrict__ B1, const float* __restrict__ W_hh,
                        ushort* __restrict__ Bc) {
    int idx = blockIdx.x * blockDim.x + threadIdx.x;
    if (idx >= 2 * 2 * 192 * 64) return;
    int lane = idx & 63;
    int slot = (idx >> 6) % 192;
    int dhalf = ((idx >> 6) / 192) % 2;
    int t = idx / (64 * 192 * 2);
    int g = slot / 12, n = slot % 12;
    int mode, kb;  // 0=C1, 1=C2_hi, 2=W_hh, 3=C2_lo
    if (g < 4) { mode = 0; kb = g; }
    else {
        int q = (g - 4) / 3, r = (g - 4) % 3;
        kb = q;
        mode = (r == 0) ? 1 : ((r == 1) ? 2 : 3);
    }
    int gate = n >> 2, dn = n & 3;
    int d = dhalf * 64 + dn * 16 + (lane & 15);
    int kbase = kb * 32 + (lane >> 4) * 8;
    ushort* dst = Bc + (size_t)idx * 8;
#pragma unroll
    for (int e = 0; e < 8; e++) {
        int k = kbase + e;  // 0..127 within slab
        float v;
        if (mode == 0) {
            v = B1[((size_t)t * K2 + k) * G3 + gate * 128 + d];
        } else if (mode == 2) {
            v = W_hh[((size_t)t * G3 + gate * 128 + d) * HD + k];
        } else {
            float full = B1[((size_t)t * K2 + 128 + k) * G3 + gate * 128 + d];
            v = (mode == 1) ? full : (full - b2f(f2b(full)));
        }
        dst[e] = f2b(v);
    }
}

// bias packs, each [t][dhalf][12][16]
__global__ void k_packbias2(const float* __restrict__ b_ih, const float* __restrict__ b_hh,
                            const float* __restrict__ c3,
                            float* __restrict__ bih_p, float* __restrict__ bhh_p,
                            float* __restrict__ c3_p) {
    int idx = blockIdx.x * blockDim.x + threadIdx.x;
    if (idx >= 2 * 2 * 12 * 16) return;
    int c = idx & 15;
    int n = (idx >> 4) % 12;
    int dhalf = ((idx >> 4) / 12) % 2;
    int t = idx / (16 * 12 * 2);
    int g = n >> 2, dn = n & 3;
    int d = dhalf * 64 + dn * 16 + c;
    bih_p[idx] = b_ih[t * G3 + g * 128 + d];
    bhh_p[idx] = b_hh[t * G3 + g * 128 + d];
    c3_p[idx]  = c3[t * G3 + g * 128 + d];
}

// ---------------- h f32 -> bf16 (for gathers) ----------------
__global__ void k_h2b(const float* __restrict__ h, ushort* __restrict__ hb) {
    int i = blockIdx.x * blockDim.x + threadIdx.x;
    if (i >= NN * HD / 4) return;
    float4 v = reinterpret_cast<const float4*>(h)[i];
    ushort4 o;
    o.x = f2b(v.x); o.y = f2b(v.y); o.z = f2b(v.z); o.w = f2b(v.w);
    reinterpret_cast<ushort4*>(hb)[i] = o;
}

// ---------------- prep: A rows [s | (deg*h)_hi | (deg*h)_lo | h_hi] bf16 ----------------
__global__ void k_prep(const ushort* __restrict__ hb, const float* __restrict__ hf,
                       const int* __restrict__ off, const int* __restrict__ deg,
                       const int* __restrict__ csr, ushort* __restrict__ Abf) {
    int wv = (blockIdx.x * blockDim.x + threadIdx.x) >> 6;
    int lane = threadIdx.x & 63;
    if (wv >= NN) return;
    int st = off[wv];
    int dg = deg[wv];
    float a0 = 0.f, a1 = 0.f;
    int j = 0;
    for (; j + 8 <= dg; j += 8) {
        uint v[8];
#pragma unroll
        for (int q = 0; q < 8; q++) {
            int s = csr[st + j + q];
            v[q] = *reinterpret_cast<const uint*>(hb + (size_t)s * HD + lane * 2);
        }
#pragma unroll
        for (int q = 0; q < 8; q++) {
            a0 += b2f((ushort)(v[q] & 0xffff));
            a1 += b2f((ushort)(v[q] >> 16));
        }
    }
    for (; j < dg; j++) {
        int s = csr[st + j];
        uint v = *reinterpret_cast<const uint*>(hb + (size_t)s * HD + lane * 2);
        a0 += b2f((ushort)(v & 0xffff));
        a1 += b2f((ushort)(v >> 16));
    }
    uint* arow = reinterpret_cast<uint*>(Abf + (size_t)wv * 512);
    arow[lane] = (uint)f2b(a0) | ((uint)f2b(a1) << 16);
    float2 hv = *reinterpret_cast<const float2*>(hf + (size_t)wv * HD + lane * 2);
    float dgf = (float)dg;
    float dh0 = dgf * hv.x, dh1 = dgf * hv.y;
    ushort p0 = f2b(dh0), p1 = f2b(dh1);
    ushort l0 = f2b(dh0 - b2f(p0)), l1 = f2b(dh1 - b2f(p1));
    arow[64 + lane]  = (uint)p0 | ((uint)p1 << 16);
    arow[128 + lane] = (uint)l0 | ((uint)l1 << 16);
    arow[192 + lane] = (uint)f2b(hv.x) | ((uint)f2b(hv.y) << 16);
}

// ---------------- fused MFMA GEMM + GRU, LDS-staged B via global_load_lds ----------------
// grid (782, 2); block 256 (4 waves); wave owns 16 rows x its d-half.
// B streamed through LDS in 8 double-buffered chunks of 24 slots (24KB each).
// STAGE: wave w loads segments w*6..w*6+5 of chunk c; LDS dest is wave-uniform
// base (global_load_lds writes base + lane*16), global src is per-lane.
#define STAGE(c)                                                          \
    _Pragma("unroll") for (int i = 0; i < 6; i++) {                       \
        int seg = w * 6 + i;                                              \
        gl_lds16(Bg + (size_t)(c) * 12288 + seg * 512 + lane * 8,         \
                 &Bs[(c) & 1][seg * 512]);                                \
    }

#define GROUP(p, a1off, dual, a2off, ACC)                                 \
    do {                                                                  \
        s16x8 a1 = ap[(a1off) + lhi];                                     \
        s16x8 a2 = (dual) ? ap[(a2off) + lhi] : a1;                       \
        _Pragma("unroll") for (int n = 0; n < 12; n++) {                  \
            s16x8 b = *reinterpret_cast<const s16x8*>(                    \
                &bufc[((p) * 12 + n) * 512 + lane * 8]);                  \
            ACC[n] = __builtin_amdgcn_mfma_f32_16x16x32_bf16(a1, b, ACC[n], 0, 0, 0); \
            if (dual)                                                     \
                ACC[n] = __builtin_amdgcn_mfma_f32_16x16x32_bf16(a2, b, ACC[n], 0, 0, 0); \
        }                                                                 \
    } while (0)

#define CHUNK(c, ...)                                                     \
    {                                                                     \
        if ((c) < 7) { STAGE((c) + 1); }                                  \
        const ushort* bufc = &Bs[(c) & 1][0];                             \
        __VA_ARGS__                                                       \
        __syncthreads();                                                  \
    }

__global__ __launch_bounds__(256) void k_fused(
    const ushort* __restrict__ Abf,     // [NN][512] bf16
    const ushort* __restrict__ Bc_t,    // [dhalf][192][512] bf16 (this t)
    const float* __restrict__ bih_t,    // [dhalf][12][16]
    const float* __restrict__ bhh_t,
    const float* __restrict__ c3_t,
    const int* __restrict__ deg,
    const float* __restrict__ hcur,     // [NN][128] f32
    float* __restrict__ hout,           // [NN][128] f32
    ushort* __restrict__ hb_out)        // [NN][128] bf16
{
    __shared__ __align__(16) ushort Bs[2][24 * 512];

    int tid = threadIdx.x;
    int m0 = blockIdx.x * 64;
    int dhalf = blockIdx.y;
    int w = tid >> 6;
    int lane = tid & 63;
    int lhi = lane >> 4;
    int col = lane & 15;
    int rowbase = m0 + w * 16;

    int ar = rowbase + col;
    int armin = ar < NN ? ar : NN - 1;
    const s16x8* ap = reinterpret_cast<const s16x8*>(Abf + (size_t)armin * 512);
    const ushort* Bg = Bc_t + (size_t)dhalf * 192 * 512;

    f32x4 accI[12], accH[12];
#pragma unroll
    for (int i = 0; i < 12; i++) {
        accI[i] = f32x4{0.f, 0.f, 0.f, 0.f};
        accH[i] = f32x4{0.f, 0.f, 0.f, 0.f};
    }

    // prologue: stage chunk 0 (syncthreads drains vmcnt before barrier)
    STAGE(0);
    __syncthreads();

    // A-frag s16x8 offsets: s slab 0..15, dh_hi 16..31, dh_lo 32..47, h_hi 48..63
    CHUNK(0, GROUP(0, 0, 0, 0, accI); GROUP(1, 4, 0, 0, accI);)     // C1 k0, C1 k1
    CHUNK(1, GROUP(0, 8, 0, 0, accI); GROUP(1, 12, 0, 0, accI);)    // C1 k2, C1 k3
    CHUNK(2, GROUP(0, 16, 1, 32, accI); GROUP(1, 48, 0, 0, accH);)  // C2hi k0 (dual), Whh k0
    CHUNK(3, GROUP(0, 16, 0, 0, accI); GROUP(1, 20, 1, 36, accI);)  // C2lo k0, C2hi k1 (dual)
    CHUNK(4, GROUP(0, 52, 0, 0, accH); GROUP(1, 20, 0, 0, accI);)   // Whh k1, C2lo k1
    CHUNK(5, GROUP(0, 24, 1, 40, accI); GROUP(1, 56, 0, 0, accH);)  // C2hi k2 (dual), Whh k2
    CHUNK(6, GROUP(0, 24, 0, 0, accI); GROUP(1, 28, 1, 44, accI);)  // C2lo k2, C2hi k3 (dual)
    CHUNK(7, GROUP(0, 60, 0, 0, accH); GROUP(1, 28, 0, 0, accI);)   // Whh k3, C2lo k3

    // epilogue: GRU in-register
    float bih[3][4], bhh[3][4], c3v[3][4];
#pragma unroll
    for (int g = 0; g < 3; g++)
#pragma unroll
        for (int dn = 0; dn < 4; dn++) {
            int o = (dhalf * 12 + g * 4 + dn) * 16 + col;
            bih[g][dn] = bih_t[o];
            bhh[g][dn] = bhh_t[o];
            c3v[g][dn] = c3_t[o];
        }

    int rbase0 = rowbase + (lhi << 2);
#pragma unroll
    for (int r = 0; r < 4; r++) {
        int m = rbase0 + r;
        bool wr = m < NN;
        int mm = wr ? m : 0;
        int dgi = deg[mm];
        float dgf = (float)dgi;
#pragma unroll
        for (int dn = 0; dn < 4; dn++) {
            int d = (dhalf << 6) + (dn << 4) + col;
            float hv = hcur[(size_t)mm * HD + d];
            float ir  = accI[dn][r]     + dgf * c3v[0][dn] + bih[0][dn];
            float iz  = accI[4 + dn][r] + dgf * c3v[1][dn] + bih[1][dn];
            float in_ = accI[8 + dn][r] + dgf * c3v[2][dn] + bih[2][dn];
            float hr = accH[dn][r]     + bhh[0][dn];
            float hz = accH[4 + dn][r] + bhh[1][dn];
            float hn = accH[8 + dn][r] + bhh[2][dn];
            float rg = 1.f / (1.f + expf(-(ir + hr)));
            float zg = 1.f / (1.f + expf(-(iz + hz)));
            float ng = tanhf(in_ + rg * hn);
            float hnew = (1.f - zg) * ng + zg * hv;
            float res = (dgi > 0) ? hnew : hv;
            if (wr) {
                hout[(size_t)m * HD + d] = res;
                hb_out[(size_t)m * HD + d] = f2b(res);
            }
        }
    }
}

extern "C" void kernel_launch(void* const* d_in, const int* in_sizes, int n_in,
                              void* d_out, int out_size, void* d_ws, size_t ws_size,
                              hipStream_t stream) {
    const float* h_in  = (const float*)d_in[0];
    const int*   edges = (const int*)d_in[1];
    const float* W_msg = (const float*)d_in[2];
    const float* b_msg = (const float*)d_in[3];
    const float* W_ih  = (const float*)d_in[4];
    const float* W_hh  = (const float*)d_in[5];
    const float* b_ih  = (const float*)d_in[6];
    const float* b_hh  = (const float*)d_in[7];
    float* out = (float*)d_out;

    char* p = (char*)d_ws;
    auto alloc = [&](size_t bytes) {
        void* r = (void*)p;
        p += (bytes + 255) / 256 * 256;
        return r;
    };
    int*    deg     = (int*)alloc((size_t)(NN + 1) * 4);  // +1: counter
    int*    off     = (int*)alloc((size_t)NN * 4);
    int*    cur     = (int*)alloc((size_t)NN * 4);
    int*    csr_src = (int*)alloc((size_t)NE * 4);
    float*  B1      = (float*)alloc((size_t)2 * K2 * G3 * 4);
    float*  c3      = (float*)alloc((size_t)2 * G3 * 4);
    ushort* Bc      = (ushort*)alloc((size_t)2 * 2 * 192 * 512 * 2);
    float*  bih_p   = (float*)alloc((size_t)2 * 2 * 12 * 16 * 4);
    float*  bhh_p   = (float*)alloc((size_t)2 * 2 * 12 * 16 * 4);
    float*  c3_p    = (float*)alloc((size_t)2 * 2 * 12 * 16 * 4);
    ushort* hb0     = (ushort*)alloc((size_t)NN * HD * 2);
    ushort* hb1     = (ushort*)alloc((size_t)NN * HD * 2);
    ushort* Abf     = (ushort*)alloc((size_t)NN * 512 * 2);
    float*  h1      = (float*)alloc((size_t)NN * HD * 4);
    int*    counter = deg + NN;

    hipMemsetAsync(deg, 0, (size_t)(NN + 1) * 4, stream);
    k_deg<<<(NE + 255) / 256, 256, 0, stream>>>(edges, deg);
    k_off<<<(NN + 255) / 256, 256, 0, stream>>>(deg, off, cur, counter);
    k_fill<<<(NE + 255) / 256, 256, 0, stream>>>(edges, cur, csr_src);
    k_comb1<<<(2 * K2 * G3 + 255) / 256, 256, 0, stream>>>(W_ih, W_msg, B1);
    k_comb3<<<(2 * G3 + 255) / 256, 256, 0, stream>>>(W_ih, b_msg, c3);
    k_pack3<<<(2 * 2 * 192 * 64 + 255) / 256, 256, 0, stream>>>(B1, W_hh, Bc);
    k_packbias2<<<(2 * 2 * 12 * 16 + 255) / 256, 256, 0, stream>>>(b_ih, b_hh, c3,
                                                                   bih_p, bhh_p, c3_p);
    k_h2b<<<(NN * HD / 4 + 255) / 256, 256, 0, stream>>>(h_in, hb0);

    dim3 fgrid((NN + 63) / 64, 2);
    const size_t BcT = (size_t)2 * 192 * 512;   // ushort units per t
    const size_t biasT = (size_t)2 * 12 * 16;

    // step 0
    k_prep<<<(NN * 64 + 255) / 256, 256, 0, stream>>>(hb0, h_in, off, deg, csr_src, Abf);
    k_fused<<<fgrid, 256, 0, stream>>>(Abf, Bc, bih_p, bhh_p, c3_p, deg, h_in, h1, hb1);
    // step 1 (hb_out reuses hb0; it is rebuilt by k_h2b every launch)
    k_prep<<<(NN * 64 + 255) / 256, 256, 0, stream>>>(hb1, h1, off, deg, csr_src, Abf);
    k_fused<<<fgrid, 256, 0, stream>>>(Abf, Bc + BcT, bih_p + biasT, bhh_p + biasT,
                                       c3_p + biasT, deg, h1, out, hb0);
}